// Round 1
// baseline (400.311 us; speedup 1.0000x reference)
//
#include <hip/hip_runtime.h>
#include <math.h>

#define KCLS  50000
#define KP    50048   // KCLS padded to multiple of 128 for the GEMM class dim
#define DIM   128
#define BATCH 1024
#define MAXD  16

#define NBLK_N   (KP / 128)       // 391 column blocks in the GEMM
#define NBP      (NBLK_N * 2)     // 782 partial (m,s) pairs per row (2 col-waves/block)
#define CLS_BLOCKS (KP / 4)       // 12512 aw blocks (4 classes per 256-thr block)
#define XB_BLOCKS  (BATCH * DIM / 1024)  // 128 folded x-conversion blocks

typedef __attribute__((ext_vector_type(8))) short short8;
typedef __attribute__((ext_vector_type(4))) float floatx4;

// round-to-nearest-even float -> bf16 bits (inputs are finite)
__device__ __forceinline__ unsigned short f2bf(float f) {
    unsigned u = __float_as_uint(f);
    u += 0x7fffu + ((u >> 16) & 1u);
    return (unsigned short)(u >> 16);
}

// ---------------------------------------------------------------------------
// Kernel 1: added_weights[k] = weights[k] + sum_{p<len} weights[path_idx[k,p]]
// ONE class per 64-lane wave (float2/lane = one 512B row) so the path loop
// trip count is wave-uniform (the old 2-classes-per-wave layout ran
// E[max(len0,len1)] ~ 10.1 iters for E[len] = 7.5 useful — ~35% idle).
// 2-way unrolled path loop for load ILP. Emits bf16 copy (pad rows zeroed).
// Blocks >= CLS_BLOCKS convert x -> bf16 (folded to save a launch).
__global__ __launch_bounds__(256) void aw_kernel(
    const float* __restrict__ weights, const int* __restrict__ path_idx,
    const int* __restrict__ path_len, float* __restrict__ aw,
    unsigned short* __restrict__ awb,
    const float* __restrict__ x, unsigned short* __restrict__ xb)
{
    int t = threadIdx.x;

    if (blockIdx.x >= CLS_BLOCKS) {   // folded x fp32->bf16 (131072 elements)
        int i = ((blockIdx.x - CLS_BLOCKS) * 256 + t) * 4;
        float4 v = *(const float4*)(x + i);
        ushort4 hv = { f2bf(v.x), f2bf(v.y), f2bf(v.z), f2bf(v.w) };
        *(ushort4*)(xb + i) = hv;
        return;
    }

    int w = t >> 6, lane = t & 63;
    int k = blockIdx.x * 4 + w;
    int col = lane * 2;

    if (k >= KCLS) {                  // zero-fill bf16 pad rows [KCLS, KP)
        ushort2 z; z.x = 0; z.y = 0;
        *(ushort2*)(awb + (size_t)k * DIM + col) = z;
        return;
    }

    float2 acc = *(const float2*)(weights + (size_t)k * DIM + col);
    int len = path_len[k];
    const int* pp = path_idx + (size_t)k * MAXD;

    int p = 0;
    for (; p + 2 <= len; p += 2) {    // 2-deep: both row loads in flight
        int i0 = pp[p], i1 = pp[p + 1];
        float2 a = *(const float2*)(weights + (size_t)i0 * DIM + col);
        float2 b = *(const float2*)(weights + (size_t)i1 * DIM + col);
        acc.x += a.x + b.x;
        acc.y += a.y + b.y;
    }
    if (p < len) {
        int i0 = pp[p];
        float2 a = *(const float2*)(weights + (size_t)i0 * DIM + col);
        acc.x += a.x;
        acc.y += a.y;
    }

    *(float2*)(aw + (size_t)k * DIM + col) = acc;
    ushort2 hv; hv.x = f2bf(acc.x); hv.y = f2bf(acc.y);
    *(ushort2*)(awb + (size_t)k * DIM + col) = hv;
}

// ---------------------------------------------------------------------------
// Kernel 2: logits = Xb · Wb^T via bf16 MFMA 16x16x32.
// 128x128 block tile, 4 waves in 2x2, each wave 64x64 = 4x4 16x16 tiles.
// PART: fused LSE-partial epilogue — per output row, reduce max and
// sum(exp(v-max)) over the wave's 64 cols (shfl_xor across the 16 r-lanes)
// and emit one (m,s) pair per (row, col-wave) to `part`. This removes the
// separate 204.8 MB logits re-read pass.
template<bool PART>
__global__ __launch_bounds__(256) void gemm_kernel(
    const unsigned short* __restrict__ Xb,   // [BATCH][DIM] bf16
    const unsigned short* __restrict__ Wb,   // [KP][DIM] bf16
    float* __restrict__ logits,              // [BATCH][KCLS]
    float2* __restrict__ part)               // [BATCH][NBP] (m, sumexp)
{
    int tid = threadIdx.x;
    int wave = tid >> 6, lane = tid & 63;
    int r = lane & 15, quad = lane >> 4;
    int m0 = blockIdx.y * 128 + (wave >> 1) * 64;
    int n0 = blockIdx.x * 128 + (wave & 1) * 64;

    const unsigned short* ap = Xb + (size_t)(m0 + r) * DIM + quad * 8;
    const unsigned short* bp = Wb + (size_t)(n0 + r) * DIM + quad * 8;

    floatx4 acc[4][4];
    #pragma unroll
    for (int i = 0; i < 4; ++i)
        #pragma unroll
        for (int j = 0; j < 4; ++j)
            acc[i][j] = (floatx4){0.f, 0.f, 0.f, 0.f};

    #pragma unroll
    for (int kk = 0; kk < 4; ++kk) {
        short8 a[4], b[4];
        #pragma unroll
        for (int i = 0; i < 4; ++i)
            a[i] = *(const short8*)(ap + (size_t)(i * 16) * DIM + kk * 32);
        #pragma unroll
        for (int j = 0; j < 4; ++j)
            b[j] = *(const short8*)(bp + (size_t)(j * 16) * DIM + kk * 32);
        #pragma unroll
        for (int i = 0; i < 4; ++i)
            #pragma unroll
            for (int j = 0; j < 4; ++j)
                acc[i][j] = __builtin_amdgcn_mfma_f32_16x16x32_bf16(
                    a[i], b[j], acc[i][j], 0, 0, 0);
    }

    #pragma unroll
    for (int i = 0; i < 4; ++i) {
        int mrow = m0 + i * 16 + quad * 4;

        // store this row-group's 4x4 col tiles
        #pragma unroll
        for (int j = 0; j < 4; ++j) {
            int col = n0 + j * 16 + r;
            if (col < KCLS) {
                float* cp = logits + (size_t)mrow * KCLS + col;
                #pragma unroll
                for (int reg = 0; reg < 4; ++reg)
                    cp[(size_t)reg * KCLS] = acc[i][j][reg];
            }
        }

        if constexpr (PART) {
            // per-row (over the wave's 64 cols) max + sum(exp(v-max))
            #pragma unroll
            for (int reg = 0; reg < 4; ++reg) {
                float v[4];
                #pragma unroll
                for (int j = 0; j < 4; ++j) {
                    int col = n0 + j * 16 + r;
                    v[j] = (col < KCLS) ? acc[i][j][reg] : -INFINITY;
                }
                // j==0 col = n0+r < KCLS always (worst case 49984+15), so mx finite
                float mx = fmaxf(fmaxf(v[0], v[1]), fmaxf(v[2], v[3]));
                #pragma unroll
                for (int off = 8; off; off >>= 1)
                    mx = fmaxf(mx, __shfl_xor(mx, off));
                float s = __expf(v[0] - mx) + __expf(v[1] - mx)
                        + __expf(v[2] - mx) + __expf(v[3] - mx);
                #pragma unroll
                for (int off = 8; off; off >>= 1)
                    s += __shfl_xor(s, off);
                if (r == 0)
                    part[(size_t)(mrow + reg) * NBP + blockIdx.x * 2 + (wave & 1)]
                        = make_float2(mx, s);
            }
        }
    }
}

// ---------------------------------------------------------------------------
// Kernel 3 (fused path): reduce NBP=782 (m,s) partials per row -> lse -> loss.
// One wave per row; ~6.4 MB total read (vs 204.8 MB logits re-read).
__global__ __launch_bounds__(256) void lsereduce_kernel(
    const float2* __restrict__ part, const float* __restrict__ logits,
    const int* __restrict__ y, float* __restrict__ loss)
{
    int b = blockIdx.x * 4 + (threadIdx.x >> 6);
    int lane = threadIdx.x & 63;
    const float2* pr = part + (size_t)b * NBP;

    float m = -INFINITY, s = 0.f;
    for (int i = lane; i < NBP; i += 64) {   // every lane gets >=12 -> m finite
        float2 pv = pr[i];
        if (pv.x > m) {
            s = s * __expf(m - pv.x) + pv.y;
            m = pv.x;
        } else {
            s += pv.y * __expf(pv.x - m);
        }
    }
    #pragma unroll
    for (int off = 32; off; off >>= 1) {
        float m2 = __shfl_xor(m, off);
        float s2 = __shfl_xor(s, off);
        float M = fmaxf(m, m2);
        s = s * __expf(m - M) + s2 * __expf(m2 - M);
        m = M;
    }
    if (lane == 0) {
        float lse = m + __logf(s);
        float ly = logits[(size_t)b * KCLS + y[b]];
        atomicAdd(loss, (lse - ly) * (1.0f / BATCH));
    }
}

// ---------------------------------------------------------------------------
// Fallback (workspace too small for partials): per-row logsumexp over logits.
__global__ __launch_bounds__(256) void lse_kernel(
    const float* __restrict__ logits, const int* __restrict__ y,
    float* __restrict__ loss)
{
    int b = blockIdx.x;
    const float* row = logits + (size_t)b * KCLS;
    float m = -INFINITY, s = 0.f;

    auto upd = [&](float v) {
        if (v <= m) {
            s += __expf(v - m);
        } else {
            s = s * __expf(m - v) + 1.f;
            m = v;
        }
    };

    if (threadIdx.x < 3) upd(row[threadIdx.x]);
    const float4* rv = (const float4*)(row + 3);
    for (int i = threadIdx.x; i < 12499; i += 256) {
        float4 v = rv[i];
        upd(v.x); upd(v.y); upd(v.z); upd(v.w);
    }
    if (threadIdx.x == 3) upd(row[49999]);

    #pragma unroll
    for (int off = 32; off > 0; off >>= 1) {
        float m2 = __shfl_down(m, off);
        float s2 = __shfl_down(s, off);
        float M = fmaxf(m, m2);
        s = s * __expf(m - M) + s2 * __expf(m2 - M);
        m = M;
    }
    __shared__ float sm[4], ss[4];
    int w = threadIdx.x >> 6, l = threadIdx.x & 63;
    if (l == 0) { sm[w] = m; ss[w] = s; }
    __syncthreads();
    if (threadIdx.x == 0) {
        m = sm[0]; s = ss[0];
        #pragma unroll
        for (int i = 1; i < 4; ++i) {
            float M = fmaxf(m, sm[i]);
            s = s * __expf(m - M) + ss[i] * __expf(sm[i] - M);
            m = M;
        }
        float lse = m + __logf(s);
        float ly = row[y[b]];
        atomicAdd(loss, (lse - ly) * (1.0f / BATCH));
    }
}

// ---------------------------------------------------------------------------
extern "C" void kernel_launch(void* const* d_in, const int* in_sizes, int n_in,
                              void* d_out, int out_size, void* d_ws, size_t ws_size,
                              hipStream_t stream)
{
    const float* weights  = (const float*)d_in[0];   // [65536][128]
    const float* x        = (const float*)d_in[1];   // [1024][128]
    const int*   y        = (const int*)d_in[2];     // [1024]
    const int*   path_idx = (const int*)d_in[3];     // [50000][16]
    const int*   path_len = (const int*)d_in[4];     // [50000]

    float* out    = (float*)d_out;
    float* loss   = out;                                  // [1]
    float* logits = out + 1;                              // [1024][50000]
    float* aw     = out + 1 + (size_t)BATCH * KCLS;       // [50000][128]

    size_t awb_sz  = (size_t)KP * DIM * sizeof(unsigned short);     // 12.8 MB
    size_t xb_sz   = (size_t)BATCH * DIM * sizeof(unsigned short);  // 0.26 MB
    size_t part_sz = (size_t)BATCH * NBP * sizeof(float2);          // 6.4 MB

    unsigned short* awb = (unsigned short*)d_ws;
    unsigned short* xb  = awb + (size_t)KP * DIM;
    float2* part = (float2*)((char*)d_ws + awb_sz + xb_sz);
    bool fused = ws_size >= awb_sz + xb_sz + part_sz;

    hipMemsetAsync(loss, 0, sizeof(float), stream);

    aw_kernel<<<CLS_BLOCKS + XB_BLOCKS, 256, 0, stream>>>(
        weights, path_idx, path_len, aw, awb, x, xb);

    if (fused) {
        gemm_kernel<true><<<dim3(NBLK_N, BATCH / 128), 256, 0, stream>>>(
            xb, awb, logits, part);
        lsereduce_kernel<<<BATCH / 4, 256, 0, stream>>>(part, logits, y, loss);
    } else {
        gemm_kernel<false><<<dim3(NBLK_N, BATCH / 128), 256, 0, stream>>>(
            xb, awb, logits, nullptr);
        lse_kernel<<<BATCH, 256, 0, stream>>>(logits, y, loss);
    }
}